// Round 4
// baseline (258.870 us; speedup 1.0000x reference)
//
#include <hip/hip_runtime.h>
#include <hip/hip_bf16.h>
#include <math.h>

#define B_   32
#define CIN  3
#define H_   224
#define W_   224
#define OC   192
#define OH   112
#define OW   112
#define PH   56
#define PW   56
#define NSP  (B_*OH*OW)          // 401408 elements per channel for BN stats
#define PLANE (OH*OW)            // 12544
#define LROW 116                 // padded LDS row stride (floats): <=2-way conflicts (free)
#define LPAD 8                   // leading pad floats (covers col -2 reads, 16B alignment)
#define OCG  8                   // oc groups in conv
#define OCPG (OC / OCG)          // 24 ocs per block

static __device__ __forceinline__ unsigned short f2bf(float f) {
    __hip_bfloat16 h = __float2bfloat16(f);   // RNE
    return *reinterpret_cast<unsigned short*>(&h);
}
static __device__ __forceinline__ float bfbits2f(unsigned short u) {
    unsigned int v = ((unsigned int)u) << 16;
    return *reinterpret_cast<float*>(&v);
}

static __device__ __forceinline__ float fexp2(float x) {
#if __has_builtin(__builtin_amdgcn_exp2f)
    return __builtin_amdgcn_exp2f(x);
#else
    return exp2f(x);
#endif
}
static __device__ __forceinline__ float frcp(float x) {
#if __has_builtin(__builtin_amdgcn_rcpf)
    return __builtin_amdgcn_rcpf(x);
#else
    return 1.0f / x;
#endif
}

// tanh-form GELU: x * sigmoid(2*c1*(x + 0.044715 x^3)), via exp2 (+rcp).
static __device__ __forceinline__ float fast_gelu(float x) {
    float x2 = x * x;
    float inner = fmaf(0.044715f * x2, x, x);
    float e = fexp2(inner * 2.3022082f);      // 2*0.7978845608*log2(e)
    float r = frcp(1.0f + e);
    return x * (e * r);
}

// ---------------- K0: zero the stats accumulators (ws is poisoned 0xAA) ----
__global__ void zero_stats(float* stats) {
    for (int i = threadIdx.x; i < 384; i += 256) stats[i] = 0.f;
}

// ---------------- K1: conv 3x3 s2 p1 + bias + fused BN stats ---------------
// Grid: 392 spatial chunks x 8 oc-groups = 3136 blocks, 256 threads.
// Each thread: 4 consecutive ow, 24 ocs. 81 x-taps in registers.
// Stats (sum, sumsq per channel) from PRE-round f32 values: butterfly
// within wave -> LDS per-wave partial -> one atomicAdd per (block, oc).
__global__ __launch_bounds__(256) void conv_kernel(
    const float* __restrict__ x, const float* __restrict__ w,
    const float* __restrict__ bias, __hip_bfloat16* __restrict__ y,
    float* __restrict__ stats)
{
    __shared__ float lsum[4][OCPG][2];

    int gb = blockIdx.x;
    int og = gb & (OCG - 1);                     // oc group (fastest varying)
    int sp = gb >> 3;                            // spatial chunk 0..391
    int tid = threadIdx.x;

    int spatial = sp * 256 + tid;                // 0..100351
    int owg = spatial % (OW / 4);
    int t   = spatial / (OW / 4);
    int oh  = t % OH;
    int b   = t / OH;
    int ow0 = owg * 4;

    int ih0 = 2 * oh  - 1;
    int iw0 = 2 * ow0 - 1;

    float xv[CIN][3][9];
    #pragma unroll
    for (int c = 0; c < CIN; ++c) {
        #pragma unroll
        for (int r = 0; r < 3; ++r) {
            int ih = ih0 + r;
            bool rv = (ih >= 0) && (ih < H_);
            const float* xrow = x + (((size_t)b * CIN + c) * H_ + (rv ? ih : 0)) * W_;
            #pragma unroll
            for (int j = 0; j < 9; ++j) {
                int iw = iw0 + j;
                bool v = rv && (iw >= 0) && (iw < W_);
                xv[c][r][j] = v ? xrow[iw] : 0.f;
            }
        }
    }

    int oc0 = og * OCPG;
    int ybase = (b * OC + oc0) * PLANE + oh * OW + ow0;
    int wave = tid >> 6;
    int lane = tid & 63;

    for (int ocl = 0; ocl < OCPG; ++ocl) {
        int oc = oc0 + ocl;
        float bs = bias[oc];
        float a0 = bs, a1 = bs, a2 = bs, a3 = bs;
        const float* wp = w + oc * 27;
        #pragma unroll
        for (int c = 0; c < CIN; ++c)
            #pragma unroll
            for (int r = 0; r < 3; ++r)
                #pragma unroll
                for (int j = 0; j < 3; ++j) {
                    float wv = wp[c * 9 + r * 3 + j];
                    a0 = fmaf(wv, xv[c][r][j + 0], a0);
                    a1 = fmaf(wv, xv[c][r][j + 2], a1);
                    a2 = fmaf(wv, xv[c][r][j + 4], a2);
                    a3 = fmaf(wv, xv[c][r][j + 6], a3);
                }

        // fused stats partials (pre-round f32, matches reference semantics)
        float s  = (a0 + a1) + (a2 + a3);
        float s2 = fmaf(a0, a0, fmaf(a1, a1, fmaf(a2, a2, a3 * a3)));
        #pragma unroll
        for (int off = 32; off > 0; off >>= 1) {
            s  += __shfl_xor(s,  off, 64);
            s2 += __shfl_xor(s2, off, 64);
        }
        if (lane == 0) { lsum[wave][ocl][0] = s; lsum[wave][ocl][1] = s2; }

        ushort4 p;
        p.x = f2bf(a0); p.y = f2bf(a1); p.z = f2bf(a2); p.w = f2bf(a3);
        *reinterpret_cast<ushort4*>(
            reinterpret_cast<unsigned short*>(y) + ybase + ocl * PLANE) = p;
    }

    __syncthreads();
    if (tid < OCPG * 2) {                        // 48 threads: 24 ocs x {sum, sumsq}
        int ocl = tid >> 1, which = tid & 1;
        float v = lsum[0][ocl][which] + lsum[1][ocl][which] +
                  lsum[2][ocl][which] + lsum[3][ocl][which];
        atomicAdd(&stats[which * OC + oc0 + ocl], v);
    }
}

// ---------------- K2: BN(affine)+GELU once per element (LDS) + maxpool ----
// One block per (b,oc) plane, 448 threads = 7 waves.
__global__ __launch_bounds__(448) void pool_kernel(
    const __hip_bfloat16* __restrict__ y, const float* __restrict__ stats,
    const float* __restrict__ gamma, const float* __restrict__ beta,
    float* __restrict__ out)
{
    __shared__ float g[LPAD + OH * LROW];        // 52 KB

    int plane = blockIdx.x;                      // b*OC + oc
    int oc = plane % OC;

    float mean = stats[oc] * (1.0f / (float)NSP);
    float var  = fmaf(-mean, mean, stats[OC + oc] * (1.0f / (float)NSP));
    float inv  = rsqrtf(var + 1e-5f);
    float sc   = gamma[oc] * inv;
    float sh   = fmaf(-mean, sc, beta[oc]);

    const uint2* p = reinterpret_cast<const uint2*>(
        reinterpret_cast<const unsigned short*>(y) + (size_t)plane * PLANE);

    int t = threadIdx.x;
    #pragma unroll
    for (int it = 0; it < 7; ++it) {             // 3136 groups / 448 = 7 exact
        int gi = it * 448 + t;
        uint2 v = p[gi];
        int row = gi / 28;
        int col = (gi - row * 28) * 4;
        float4 q;
        q.x = fast_gelu(fmaf(bfbits2f((unsigned short)(v.x & 0xffffu)), sc, sh));
        q.y = fast_gelu(fmaf(bfbits2f((unsigned short)(v.x >> 16)),     sc, sh));
        q.z = fast_gelu(fmaf(bfbits2f((unsigned short)(v.y & 0xffffu)), sc, sh));
        q.w = fast_gelu(fmaf(bfbits2f((unsigned short)(v.y >> 16)),     sc, sh));
        *reinterpret_cast<float4*>(&g[LPAD + row * LROW + col]) = q;
    }
    __syncthreads();

    int r = t >> 3;                              // output row 0..55
    int k = t & 7;                               // col-group 0..7
    int c0 = 14 * k - 2;

    float vm[16];
    #pragma unroll
    for (int q = 0; q < 16; ++q) vm[q] = -INFINITY;

    #pragma unroll
    for (int rr = 0; rr < 3; ++rr) {
        int row = 2 * r - 1 + rr;
        if (row < 0) continue;
        const float2* rp = reinterpret_cast<const float2*>(&g[LPAD + row * LROW + c0]);
        #pragma unroll
        for (int q = 0; q < 8; ++q) {
            float2 v = rp[q];
            vm[2 * q]     = fmaxf(vm[2 * q],     v.x);
            vm[2 * q + 1] = fmaxf(vm[2 * q + 1], v.y);
        }
    }
    if (k == 0) vm[1] = -INFINITY;

    float* op = out + (size_t)plane * (PH * PW) + r * PW + 7 * k;
    #pragma unroll
    for (int m = 0; m < 7; ++m) {
        op[m] = fmaxf(fmaxf(vm[2 * m + 1], vm[2 * m + 2]), vm[2 * m + 3]);
    }
}

extern "C" void kernel_launch(void* const* d_in, const int* in_sizes, int n_in,
                              void* d_out, int out_size, void* d_ws, size_t ws_size,
                              hipStream_t stream) {
    const float* x     = (const float*)d_in[0];
    const float* w     = (const float*)d_in[1];
    const float* bias  = (const float*)d_in[2];
    const float* gamma = (const float*)d_in[3];
    const float* beta  = (const float*)d_in[4];
    float* out = (float*)d_out;

    float* stats = (float*)d_ws;                                   // 384 floats of sums
    __hip_bfloat16* y = (__hip_bfloat16*)((char*)d_ws + 4096);     // 154.1 MB bf16

    hipLaunchKernelGGL(zero_stats, dim3(1), dim3(256), 0, stream, stats);
    hipLaunchKernelGGL(conv_kernel, dim3((B_ * OH * (OW / 4)) / 256 * OCG), dim3(256), 0,
                       stream, x, w, bias, y, stats);
    hipLaunchKernelGGL(pool_kernel, dim3(B_ * OC), dim3(448), 0, stream,
                       y, stats, gamma, beta, out);
}